// Round 18
// baseline (70.582 us; speedup 1.0000x reference)
//
#include <hip/hip_runtime.h>
#include <cstdint>
#include <cstddef>

// ===================== DIAGNOSTIC ROUND (gemm x8) ==========================
// k_gemm_heads runs its K-pipeline GREP=8 times (acc scaled 1/8 in epilogue)
// to force it above the ~43us harness poison-fills in the rocprof top-5 and
// to separate cold-miss vs steady-state cost. Revert GREP to 1 next round.
// Live change kept for future rounds: k_fc ITILE 8->16.
// ===========================================================================
#define GREP 8

#define SEQD 20
#define HID  512
#define LSEQ 2048
#define MROWS 8192
#define BM   64
#define BN   128
#define GBK  64
#define ITILE 16

typedef __attribute__((ext_vector_type(4))) float f32x4;
typedef __attribute__((ext_vector_type(8))) short bf16x8;

__device__ __forceinline__ ushort f2bf(float f) {
  union { float f; unsigned u; } v; v.f = f;
  unsigned r = v.u + 0x7fffu + ((v.u >> 16) & 1u);   // RNE
  return (ushort)(r >> 16);
}
// XOR-swizzle of byte offset b (0..127) within a 128B k-stripe, keyed by row.
// Involution on 16B-slot bits (4..6). Pre-swizzled at global write, same XOR
// at ds_read; LDS staging copies linearly (rule #21).
__device__ __forceinline__ int swzb(int row, int b) {
  return (b & 0x0F) | ((b ^ ((row & 7) << 4)) & 0x70);
}
__device__ __forceinline__ void async16(const ushort* g, ushort* l) {
  __builtin_amdgcn_global_load_lds(
      (const __attribute__((address_space(1))) unsigned*)g,
      (__attribute__((address_space(3))) unsigned*)l, 16, 0, 0);
}

// ---------------------------------------------------------------------------
// Kernel 1 (prep): UNCHANGED from R17.
// ---------------------------------------------------------------------------
__global__ __launch_bounds__(256) void k_prep(const float* __restrict__ X,
                                              const float* __restrict__ W1,
                                              const float* __restrict__ b1,
                                              const float* __restrict__ W2,
                                              ushort* __restrict__ h1,
                                              ushort* __restrict__ W2t) {
  __shared__ float Xs[16][SEQD + 1];
  __shared__ float tile[32][33];
  const int t = threadIdx.x;
  if (blockIdx.x < 512) {
    const int base = blockIdx.x * 16;
    for (int i = t; i < 16 * SEQD; i += 256) Xs[i / SEQD][i % SEQD] = X[base * SEQD + i];
    __syncthreads();
    const int m0 = (t >> 6) * 4;
    const int nl = (t & 63) * 4;
    float4 acc[4][2];
#pragma unroll
    for (int mi = 0; mi < 4; ++mi) {
      acc[mi][0] = *(const float4*)&b1[nl];
      acc[mi][1] = *(const float4*)&b1[nl + 256];
    }
#pragma unroll
    for (int k = 0; k < SEQD; ++k) {
      const float4 w0 = *(const float4*)&W1[k * HID + nl];
      const float4 w1 = *(const float4*)&W1[k * HID + nl + 256];
#pragma unroll
      for (int mi = 0; mi < 4; ++mi) {
        const float xv = Xs[m0 + mi][k];
        acc[mi][0].x += xv * w0.x; acc[mi][0].y += xv * w0.y;
        acc[mi][0].z += xv * w0.z; acc[mi][0].w += xv * w0.w;
        acc[mi][1].x += xv * w1.x; acc[mi][1].y += xv * w1.y;
        acc[mi][1].z += xv * w1.z; acc[mi][1].w += xv * w1.w;
      }
    }
#pragma unroll
    for (int mi = 0; mi < 4; ++mi) {
      const int m = base + m0 + mi;
#pragma unroll
      for (int g = 0; g < 2; ++g) {
        const float4 r = acc[mi][g];
        ushort4 o;
        o.x = f2bf(fmaxf(r.x, 0.f)); o.y = f2bf(fmaxf(r.y, 0.f));
        o.z = f2bf(fmaxf(r.z, 0.f)); o.w = f2bf(fmaxf(r.w, 0.f));
        const int k = nl + g * 256;
        const int sb = swzb(m, (k & 63) * 2);
        *(ushort4*)&h1[(size_t)m * HID + (k & ~63) + (sb >> 1)] = o;
      }
    }
  } else {
    const int c = blockIdx.x - 512;
    const int k0 = (c & 15) * 32, n0 = (c >> 4) * 32;
    const int tx = t & 31, ty = t >> 5;
#pragma unroll
    for (int r = ty; r < 32; r += 8)
      tile[r][tx] = W2[(size_t)(k0 + r) * HID + n0 + tx];
    __syncthreads();
#pragma unroll
    for (int r = ty; r < 32; r += 8) {
      const int n = n0 + r, k = k0 + tx;
      const int sb = swzb(n, (k & 63) * 2);
      W2t[(size_t)n * HID + (k & ~63) + (sb >> 1)] = f2bf(tile[tx][r]);
    }
  }
}

// ---------------------------------------------------------------------------
// Kernel 2: gemm2 + fused heads. R17 geometry/schedule; K-pipeline x GREP
// (diagnostic). Epilogue scales acc by 1/GREP.
// ---------------------------------------------------------------------------
__global__ __launch_bounds__(256, 2) void k_gemm_heads(const ushort* __restrict__ Aglob,
                                                       const ushort* __restrict__ Bglob,
                                                       const float* __restrict__ b2,
                                                       const float* __restrict__ Wss,
                                                       const float* __restrict__ Wang,
                                                       const float* __restrict__ Wc,
                                                       float* __restrict__ Hpart) {
  __shared__ ushort As[3][BM * GBK];       // 3 x 8 KB
  __shared__ ushort Bs[3][BN * GBK];       // 3 x 16 KB
  __shared__ float  comb[2][BM][8];        // 4 KB
  const int t = threadIdx.x;
  const int wave = t >> 6, lane = t & 63;
  const int l15 = lane & 15, lhi = lane >> 4;
  const int wr = wave >> 1, wc = wave & 1;
  const int swz = (blockIdx.x & 7) * 64 + (blockIdx.x >> 3);  // bijective, 512%8==0
  const int xblk = swz & 3, yblk = swz >> 2;
  const int bm = yblk * BM, bn = xblk * BN;
  const int srow = lane >> 3;
  const int scol = (lane & 7) * 8;

  f32x4 acc[2][4];
#pragma unroll
  for (int mi = 0; mi < 2; ++mi)
#pragma unroll
    for (int ni = 0; ni < 4; ++ni) acc[mi][ni] = {0.f, 0.f, 0.f, 0.f};

#define STAGE(buf, k0)                                                         \
  {                                                                            \
    _Pragma("unroll")                                                          \
    for (int rd = 0; rd < 2; ++rd) {                                           \
      const int r = rd * 32 + wave * 8 + srow;                                 \
      async16(Aglob + (size_t)(bm + r) * HID + (k0) + scol,                    \
              &As[buf][rd * 2048 + wave * 512]);                               \
    }                                                                          \
    _Pragma("unroll")                                                          \
    for (int rd = 0; rd < 4; ++rd) {                                           \
      const int r = rd * 32 + wave * 8 + srow;                                 \
      async16(Bglob + (size_t)(bn + r) * HID + (k0) + scol,                    \
              &Bs[buf][rd * 2048 + wave * 512]);                               \
    }                                                                          \
  }

#define COMPUTE(buf)                                                           \
  {                                                                            \
    _Pragma("unroll")                                                          \
    for (int kk = 0; kk < 2; ++kk) {                                           \
      bf16x8 af[2], bff[4];                                                    \
      _Pragma("unroll")                                                        \
      for (int mi = 0; mi < 2; ++mi) {                                         \
        const int row = wr * 32 + mi * 16 + l15;                               \
        af[mi] = *(const bf16x8*)&As[buf][(row * 128 + swzb(row, kk * 64 + lhi * 16)) >> 1]; \
      }                                                                        \
      _Pragma("unroll")                                                        \
      for (int ni = 0; ni < 4; ++ni) {                                         \
        const int rn = wc * 64 + ni * 16 + l15;                                \
        bff[ni] = *(const bf16x8*)&Bs[buf][(rn * 128 + swzb(rn, kk * 64 + lhi * 16)) >> 1]; \
      }                                                                        \
      _Pragma("unroll")                                                        \
      for (int mi = 0; mi < 2; ++mi)                                           \
        _Pragma("unroll")                                                      \
        for (int ni = 0; ni < 4; ++ni)                                         \
          acc[mi][ni] = __builtin_amdgcn_mfma_f32_16x16x32_bf16(af[mi], bff[ni], acc[mi][ni], 0, 0, 0); \
    }                                                                          \
  }

#define STEP(s_, WAITS_)                                                       \
  {                                                                            \
    if ((s_) + 2 < 8) STAGE(((s_) + 2) % 3, ((s_) + 2) * GBK)                  \
    asm volatile("s_waitcnt vmcnt(" WAITS_ ")" ::: "memory");                  \
    __builtin_amdgcn_s_barrier();                                              \
    COMPUTE((s_) % 3);                                                         \
    __builtin_amdgcn_s_barrier();                                              \
  }

#pragma unroll 1
  for (int rep = 0; rep < GREP; ++rep) {
    STAGE(0, 0)
    STAGE(1, GBK)
    STEP(0, "12") STEP(1, "12") STEP(2, "12") STEP(3, "12")
    STEP(4, "12") STEP(5, "12") STEP(6, "6")  STEP(7, "0")
  }
  const float rs = 1.0f / (float)GREP;

  // ---- epilogue: bias+relu, head partials, 16-lane reduce, wc-combine,
  //      deterministic coalesced plane writes ----
  float bias[4], ws0[4], ws1[4], ws2[4], wa0[4], wa1[4], wc0[4], wc1[4];
#pragma unroll
  for (int ni = 0; ni < 4; ++ni) {
    const int col = bn + wc * 64 + ni * 16 + l15;
    bias[ni] = b2[col];
    ws0[ni] = Wss[col * 3 + 0]; ws1[ni] = Wss[col * 3 + 1]; ws2[ni] = Wss[col * 3 + 2];
    wa0[ni] = Wang[col * 2 + 0]; wa1[ni] = Wang[col * 2 + 1];
    wc0[ni] = Wc[col]; wc1[ni] = Wc[HID + col];
  }
#pragma unroll
  for (int mi = 0; mi < 2; ++mi) {
#pragma unroll
    for (int j = 0; j < 4; ++j) {
      float p0 = 0, p1 = 0, p2 = 0, p3 = 0, p4 = 0, p5 = 0, p6 = 0;
#pragma unroll
      for (int ni = 0; ni < 4; ++ni) {
        const float v = fmaxf(acc[mi][ni][j] * rs + bias[ni], 0.f);
        p0 += v * ws0[ni]; p1 += v * ws1[ni]; p2 += v * ws2[ni];
        p3 += v * wa0[ni]; p4 += v * wa1[ni];
        p5 += v * wc0[ni]; p6 += v * wc1[ni];
      }
#pragma unroll
      for (int m = 1; m <= 8; m <<= 1) {
        p0 += __shfl_xor(p0, m); p1 += __shfl_xor(p1, m); p2 += __shfl_xor(p2, m);
        p3 += __shfl_xor(p3, m); p4 += __shfl_xor(p4, m);
        p5 += __shfl_xor(p5, m); p6 += __shfl_xor(p6, m);
      }
      if (l15 == 0) {
        const int lr = wr * 32 + mi * 16 + lhi * 4 + j;   // local row 0..63
        comb[wc][lr][0] = p0; comb[wc][lr][1] = p1; comb[wc][lr][2] = p2;
        comb[wc][lr][3] = p3; comb[wc][lr][4] = p4;
        comb[wc][lr][5] = p5; comb[wc][lr][6] = p6;
      }
    }
  }
  __syncthreads();
  if (t < BM) {
    const int row = bm + t;
#pragma unroll
    for (int q = 0; q < 7; ++q)
      Hpart[(size_t)(xblk * 7 + q) * MROWS + row] =
          comb[0][t][q] + comb[1][t][q];
  }
#undef STAGE
#undef COMPUTE
#undef STEP
}

// ---------------------------------------------------------------------------
// Kernel 3: finalize + contact. ITILE 16 (was 8): 512 blocks, halves cj
// re-staging. Nontemporal contact stores (write-once 64MB stream).
// ---------------------------------------------------------------------------
__global__ __launch_bounds__(256) void k_fc(const float* __restrict__ Hpart,
                                            const float* __restrict__ bss,
                                            const float* __restrict__ bang,
                                            const float* __restrict__ bc,
                                            float* __restrict__ ssO,
                                            float* __restrict__ angO,
                                            float* __restrict__ contact) {
  __shared__ float cj_l[LSEQ];
  __shared__ float ci_l[ITILE];
  const int blk = blockIdx.x;            // 0..511
  const int b   = blk >> 7;              // batch
  const int i0  = (blk & 127) * ITILE;
  const int t   = threadIdx.x;
  const size_t rowbase = (size_t)b * LSEQ;

  {
    const float* p0 = Hpart + (size_t)(0 * 7 + 6) * MROWS + rowbase;
    const float* p1 = Hpart + (size_t)(1 * 7 + 6) * MROWS + rowbase;
    const float* p2 = Hpart + (size_t)(2 * 7 + 6) * MROWS + rowbase;
    const float* p3 = Hpart + (size_t)(3 * 7 + 6) * MROWS + rowbase;
#pragma unroll
    for (int it = 0; it < 2; ++it) {
      const int j = it * 1024 + t * 4;
      const float4 a = *(const float4*)&p0[j];
      const float4 bq = *(const float4*)&p1[j];
      const float4 c = *(const float4*)&p2[j];
      const float4 d = *(const float4*)&p3[j];
      float4 s;
      s.x = a.x + bq.x + c.x + d.x;
      s.y = a.y + bq.y + c.y + d.y;
      s.z = a.z + bq.z + c.z + d.z;
      s.w = a.w + bq.w + c.w + d.w;
      *(float4*)&cj_l[j] = s;
    }
  }
  if (t < ITILE) {
    const size_t r = rowbase + i0 + t;
    float q[6] = {0, 0, 0, 0, 0, 0};
#pragma unroll
    for (int s = 0; s < 4; ++s)
#pragma unroll
      for (int qq = 0; qq < 6; ++qq)
        q[qq] += Hpart[(size_t)(s * 7 + qq) * MROWS + r];
    const float l0 = q[0] + bss[0], l1 = q[1] + bss[1], l2 = q[2] + bss[2];
    const float mx = fmaxf(l0, fmaxf(l1, l2));
    const float e0 = __expf(l0 - mx), e1 = __expf(l1 - mx), e2 = __expf(l2 - mx);
    const float inv = 1.f / (e0 + e1 + e2);
    ssO[r * 3 + 0] = e0 * inv;
    ssO[r * 3 + 1] = e1 * inv;
    ssO[r * 3 + 2] = e2 * inv;
    angO[r * 2 + 0] = q[3] + bang[0];
    angO[r * 2 + 1] = q[4] + bang[1];
    ci_l[t] = q[5] + bc[0];
  }
  __syncthreads();

#pragma unroll
  for (int r = 0; r < ITILE; ++r) {
    const float base = ci_l[r];
    float* orow = contact + (rowbase + i0 + r) * LSEQ;
#pragma unroll
    for (int jc = 0; jc < 2; ++jc) {
      const int j0 = jc * 1024 + t * 4;
      const float4 c4 = *(const float4*)&cj_l[j0];
      f32x4 o;
      o[0] = 1.f / (1.f + __expf(-(base + c4.x)));
      o[1] = 1.f / (1.f + __expf(-(base + c4.y)));
      o[2] = 1.f / (1.f + __expf(-(base + c4.z)));
      o[3] = 1.f / (1.f + __expf(-(base + c4.w)));
      __builtin_nontemporal_store(o, (f32x4*)&orow[j0]);
    }
  }
}

// ---------------------------------------------------------------------------
extern "C" void kernel_launch(void* const* d_in, const int* in_sizes, int n_in,
                              void* d_out, int out_size, void* d_ws, size_t ws_size,
                              hipStream_t stream) {
  const float* X    = (const float*)d_in[0];
  const float* W1   = (const float*)d_in[1];
  const float* b1   = (const float*)d_in[2];
  const float* W2   = (const float*)d_in[3];
  const float* b2   = (const float*)d_in[4];
  const float* Wss  = (const float*)d_in[5];
  const float* bss  = (const float*)d_in[6];
  const float* Wang = (const float*)d_in[7];
  const float* bang = (const float*)d_in[8];
  const float* Wc   = (const float*)d_in[9];
  const float* bc   = (const float*)d_in[10];

  float* out     = (float*)d_out;
  float* ssO     = out;                         // [8192,3]
  float* angO    = out + 24576;                 // [8192,2]
  float* contact = out + 40960;                 // [4,2048,2048]

  ushort* h1  = (ushort*)contact;                        // 8 MB  (swizzled)
  ushort* W2t = (ushort*)(contact + 2 * 1024 * 1024);    // 512 KB (swizzled)
  float* Hpart = (float*)d_ws;                           // [4][7][8192]

  k_prep<<<768, 256, 0, stream>>>(X, W1, b1, W2, h1, W2t);
  k_gemm_heads<<<512, 256, 0, stream>>>(h1, W2t, b2, Wss, Wang, Wc, Hpart);
  k_fc<<<512, 256, 0, stream>>>(Hpart, bss, bang, bc, ssO, angO, contact);
}

// Round 19
// 38.804 us; speedup vs baseline: 1.8189x; 1.8189x over previous
//
#include <hip/hip_runtime.h>
#include <cstdint>
#include <cstddef>

#define SEQD 20
#define HID  512
#define LSEQ 2048
#define MROWS 8192
#define BM   64
#define BN   128
#define GBK  64
#define ITILE 16

typedef __attribute__((ext_vector_type(4))) float f32x4;
typedef __attribute__((ext_vector_type(8))) short bf16x8;

__device__ __forceinline__ ushort f2bf(float f) {
  union { float f; unsigned u; } v; v.f = f;
  unsigned r = v.u + 0x7fffu + ((v.u >> 16) & 1u);   // RNE
  return (ushort)(r >> 16);
}
// XOR-swizzle of byte offset b (0..127) within a 128B k-stripe, keyed by row.
// Involution on 16B-slot bits (4..6). Pre-swizzled at global write, same XOR
// at ds_read; LDS staging copies linearly (rule #21).
__device__ __forceinline__ int swzb(int row, int b) {
  return (b & 0x0F) | ((b ^ ((row & 7) << 4)) & 0x70);
}
__device__ __forceinline__ void async16(const ushort* g, ushort* l) {
  __builtin_amdgcn_global_load_lds(
      (const __attribute__((address_space(1))) unsigned*)g,
      (__attribute__((address_space(3))) unsigned*)l, 16, 0, 0);
}

// ---------------------------------------------------------------------------
// Kernel 1 (prep): XCD-ALIGNED row mapping (R18 diagnostic: ~30% of h1
// survives in L2 across the kernel boundary; align writer-XCD == reader-XCD
// so the surviving lines are local to the gemm block that reads them).
// enc1 block bid writes rows base = (bid&7)*1024 + (bid>>3)*16 — the gemm
// block with the same bid&7 (same XCD under round-robin dispatch) reads
// exactly rows [1024*(bid&7), +1024). Pure index permutation; values and
// addresses unchanged.
// ---------------------------------------------------------------------------
__global__ __launch_bounds__(256) void k_prep(const float* __restrict__ X,
                                              const float* __restrict__ W1,
                                              const float* __restrict__ b1,
                                              const float* __restrict__ W2,
                                              ushort* __restrict__ h1,
                                              ushort* __restrict__ W2t) {
  __shared__ float Xs[16][SEQD + 1];
  __shared__ float tile[32][33];
  const int t = threadIdx.x;
  if (blockIdx.x < 512) {
    const int base = (blockIdx.x & 7) * 1024 + (blockIdx.x >> 3) * 16;
    for (int i = t; i < 16 * SEQD; i += 256) Xs[i / SEQD][i % SEQD] = X[(size_t)base * SEQD + i];
    __syncthreads();
    const int m0 = (t >> 6) * 4;
    const int nl = (t & 63) * 4;
    float4 acc[4][2];
#pragma unroll
    for (int mi = 0; mi < 4; ++mi) {
      acc[mi][0] = *(const float4*)&b1[nl];
      acc[mi][1] = *(const float4*)&b1[nl + 256];
    }
#pragma unroll
    for (int k = 0; k < SEQD; ++k) {
      const float4 w0 = *(const float4*)&W1[k * HID + nl];
      const float4 w1 = *(const float4*)&W1[k * HID + nl + 256];
#pragma unroll
      for (int mi = 0; mi < 4; ++mi) {
        const float xv = Xs[m0 + mi][k];
        acc[mi][0].x += xv * w0.x; acc[mi][0].y += xv * w0.y;
        acc[mi][0].z += xv * w0.z; acc[mi][0].w += xv * w0.w;
        acc[mi][1].x += xv * w1.x; acc[mi][1].y += xv * w1.y;
        acc[mi][1].z += xv * w1.z; acc[mi][1].w += xv * w1.w;
      }
    }
#pragma unroll
    for (int mi = 0; mi < 4; ++mi) {
      const int m = base + m0 + mi;
#pragma unroll
      for (int g = 0; g < 2; ++g) {
        const float4 r = acc[mi][g];
        ushort4 o;
        o.x = f2bf(fmaxf(r.x, 0.f)); o.y = f2bf(fmaxf(r.y, 0.f));
        o.z = f2bf(fmaxf(r.z, 0.f)); o.w = f2bf(fmaxf(r.w, 0.f));
        const int k = nl + g * 256;
        const int sb = swzb(m, (k & 63) * 2);
        *(ushort4*)&h1[(size_t)m * HID + (k & ~63) + (sb >> 1)] = o;
      }
    }
  } else {
    const int c = blockIdx.x - 512;
    const int k0 = (c & 15) * 32, n0 = (c >> 4) * 32;
    const int tx = t & 31, ty = t >> 5;
#pragma unroll
    for (int r = ty; r < 32; r += 8)
      tile[r][tx] = W2[(size_t)(k0 + r) * HID + n0 + tx];
    __syncthreads();
#pragma unroll
    for (int r = ty; r < 32; r += 8) {
      const int n = n0 + r, k = k0 + tx;
      const int sb = swzb(n, (k & 63) * 2);
      W2t[(size_t)n * HID + (k & ~63) + (sb >> 1)] = f2bf(tile[tx][r]);
    }
  }
}

// ---------------------------------------------------------------------------
// Kernel 2: gemm2 + fused heads. UNCHANGED from R17/R18 (GREP reverted to 1):
// BM=64 x BN=128, grid 512 = 2 blocks/CU, 3-buffer 2-deep counted-vmcnt
// pipeline, deterministic Hpart plane writes.
// ---------------------------------------------------------------------------
__global__ __launch_bounds__(256, 2) void k_gemm_heads(const ushort* __restrict__ Aglob,
                                                       const ushort* __restrict__ Bglob,
                                                       const float* __restrict__ b2,
                                                       const float* __restrict__ Wss,
                                                       const float* __restrict__ Wang,
                                                       const float* __restrict__ Wc,
                                                       float* __restrict__ Hpart) {
  __shared__ ushort As[3][BM * GBK];       // 3 x 8 KB
  __shared__ ushort Bs[3][BN * GBK];       // 3 x 16 KB
  __shared__ float  comb[2][BM][8];        // 4 KB
  const int t = threadIdx.x;
  const int wave = t >> 6, lane = t & 63;
  const int l15 = lane & 15, lhi = lane >> 4;
  const int wr = wave >> 1, wc = wave & 1;
  const int swz = (blockIdx.x & 7) * 64 + (blockIdx.x >> 3);  // bijective, 512%8==0
  const int xblk = swz & 3, yblk = swz >> 2;
  const int bm = yblk * BM, bn = xblk * BN;
  const int srow = lane >> 3;
  const int scol = (lane & 7) * 8;

  f32x4 acc[2][4];
#pragma unroll
  for (int mi = 0; mi < 2; ++mi)
#pragma unroll
    for (int ni = 0; ni < 4; ++ni) acc[mi][ni] = {0.f, 0.f, 0.f, 0.f};

#define STAGE(buf, k0)                                                         \
  {                                                                            \
    _Pragma("unroll")                                                          \
    for (int rd = 0; rd < 2; ++rd) {                                           \
      const int r = rd * 32 + wave * 8 + srow;                                 \
      async16(Aglob + (size_t)(bm + r) * HID + (k0) + scol,                    \
              &As[buf][rd * 2048 + wave * 512]);                               \
    }                                                                          \
    _Pragma("unroll")                                                          \
    for (int rd = 0; rd < 4; ++rd) {                                           \
      const int r = rd * 32 + wave * 8 + srow;                                 \
      async16(Bglob + (size_t)(bn + r) * HID + (k0) + scol,                    \
              &Bs[buf][rd * 2048 + wave * 512]);                               \
    }                                                                          \
  }

#define COMPUTE(buf)                                                           \
  {                                                                            \
    _Pragma("unroll")                                                          \
    for (int kk = 0; kk < 2; ++kk) {                                           \
      bf16x8 af[2], bff[4];                                                    \
      _Pragma("unroll")                                                        \
      for (int mi = 0; mi < 2; ++mi) {                                         \
        const int row = wr * 32 + mi * 16 + l15;                               \
        af[mi] = *(const bf16x8*)&As[buf][(row * 128 + swzb(row, kk * 64 + lhi * 16)) >> 1]; \
      }                                                                        \
      _Pragma("unroll")                                                        \
      for (int ni = 0; ni < 4; ++ni) {                                         \
        const int rn = wc * 64 + ni * 16 + l15;                                \
        bff[ni] = *(const bf16x8*)&Bs[buf][(rn * 128 + swzb(rn, kk * 64 + lhi * 16)) >> 1]; \
      }                                                                        \
      _Pragma("unroll")                                                        \
      for (int mi = 0; mi < 2; ++mi)                                           \
        _Pragma("unroll")                                                      \
        for (int ni = 0; ni < 4; ++ni)                                         \
          acc[mi][ni] = __builtin_amdgcn_mfma_f32_16x16x32_bf16(af[mi], bff[ni], acc[mi][ni], 0, 0, 0); \
    }                                                                          \
  }

#define STEP(s_, WAITS_)                                                       \
  {                                                                            \
    if ((s_) + 2 < 8) STAGE(((s_) + 2) % 3, ((s_) + 2) * GBK)                  \
    asm volatile("s_waitcnt vmcnt(" WAITS_ ")" ::: "memory");                  \
    __builtin_amdgcn_s_barrier();                                              \
    COMPUTE((s_) % 3);                                                         \
    __builtin_amdgcn_s_barrier();                                              \
  }

  STAGE(0, 0)
  STAGE(1, GBK)
  STEP(0, "12") STEP(1, "12") STEP(2, "12") STEP(3, "12")
  STEP(4, "12") STEP(5, "12") STEP(6, "6")  STEP(7, "0")

  // ---- epilogue: bias+relu, head partials, 16-lane reduce, wc-combine,
  //      deterministic coalesced plane writes ----
  float bias[4], ws0[4], ws1[4], ws2[4], wa0[4], wa1[4], wc0[4], wc1[4];
#pragma unroll
  for (int ni = 0; ni < 4; ++ni) {
    const int col = bn + wc * 64 + ni * 16 + l15;
    bias[ni] = b2[col];
    ws0[ni] = Wss[col * 3 + 0]; ws1[ni] = Wss[col * 3 + 1]; ws2[ni] = Wss[col * 3 + 2];
    wa0[ni] = Wang[col * 2 + 0]; wa1[ni] = Wang[col * 2 + 1];
    wc0[ni] = Wc[col]; wc1[ni] = Wc[HID + col];
  }
#pragma unroll
  for (int mi = 0; mi < 2; ++mi) {
#pragma unroll
    for (int j = 0; j < 4; ++j) {
      float p0 = 0, p1 = 0, p2 = 0, p3 = 0, p4 = 0, p5 = 0, p6 = 0;
#pragma unroll
      for (int ni = 0; ni < 4; ++ni) {
        const float v = fmaxf(acc[mi][ni][j] + bias[ni], 0.f);
        p0 += v * ws0[ni]; p1 += v * ws1[ni]; p2 += v * ws2[ni];
        p3 += v * wa0[ni]; p4 += v * wa1[ni];
        p5 += v * wc0[ni]; p6 += v * wc1[ni];
      }
#pragma unroll
      for (int m = 1; m <= 8; m <<= 1) {
        p0 += __shfl_xor(p0, m); p1 += __shfl_xor(p1, m); p2 += __shfl_xor(p2, m);
        p3 += __shfl_xor(p3, m); p4 += __shfl_xor(p4, m);
        p5 += __shfl_xor(p5, m); p6 += __shfl_xor(p6, m);
      }
      if (l15 == 0) {
        const int lr = wr * 32 + mi * 16 + lhi * 4 + j;   // local row 0..63
        comb[wc][lr][0] = p0; comb[wc][lr][1] = p1; comb[wc][lr][2] = p2;
        comb[wc][lr][3] = p3; comb[wc][lr][4] = p4;
        comb[wc][lr][5] = p5; comb[wc][lr][6] = p6;
      }
    }
  }
  __syncthreads();
  if (t < BM) {
    const int row = bm + t;
#pragma unroll
    for (int q = 0; q < 7; ++q)
      Hpart[(size_t)(xblk * 7 + q) * MROWS + row] =
          comb[0][t][q] + comb[1][t][q];
  }
#undef STAGE
#undef COMPUTE
#undef STEP
}

// ---------------------------------------------------------------------------
// Kernel 3: finalize + contact (ITILE=16, nontemporal stores — as R18).
// ---------------------------------------------------------------------------
__global__ __launch_bounds__(256) void k_fc(const float* __restrict__ Hpart,
                                            const float* __restrict__ bss,
                                            const float* __restrict__ bang,
                                            const float* __restrict__ bc,
                                            float* __restrict__ ssO,
                                            float* __restrict__ angO,
                                            float* __restrict__ contact) {
  __shared__ float cj_l[LSEQ];
  __shared__ float ci_l[ITILE];
  const int blk = blockIdx.x;            // 0..511
  const int b   = blk >> 7;              // batch
  const int i0  = (blk & 127) * ITILE;
  const int t   = threadIdx.x;
  const size_t rowbase = (size_t)b * LSEQ;

  {
    const float* p0 = Hpart + (size_t)(0 * 7 + 6) * MROWS + rowbase;
    const float* p1 = Hpart + (size_t)(1 * 7 + 6) * MROWS + rowbase;
    const float* p2 = Hpart + (size_t)(2 * 7 + 6) * MROWS + rowbase;
    const float* p3 = Hpart + (size_t)(3 * 7 + 6) * MROWS + rowbase;
#pragma unroll
    for (int it = 0; it < 2; ++it) {
      const int j = it * 1024 + t * 4;
      const float4 a = *(const float4*)&p0[j];
      const float4 bq = *(const float4*)&p1[j];
      const float4 c = *(const float4*)&p2[j];
      const float4 d = *(const float4*)&p3[j];
      float4 s;
      s.x = a.x + bq.x + c.x + d.x;
      s.y = a.y + bq.y + c.y + d.y;
      s.z = a.z + bq.z + c.z + d.z;
      s.w = a.w + bq.w + c.w + d.w;
      *(float4*)&cj_l[j] = s;
    }
  }
  if (t < ITILE) {
    const size_t r = rowbase + i0 + t;
    float q[6] = {0, 0, 0, 0, 0, 0};
#pragma unroll
    for (int s = 0; s < 4; ++s)
#pragma unroll
      for (int qq = 0; qq < 6; ++qq)
        q[qq] += Hpart[(size_t)(s * 7 + qq) * MROWS + r];
    const float l0 = q[0] + bss[0], l1 = q[1] + bss[1], l2 = q[2] + bss[2];
    const float mx = fmaxf(l0, fmaxf(l1, l2));
    const float e0 = __expf(l0 - mx), e1 = __expf(l1 - mx), e2 = __expf(l2 - mx);
    const float inv = 1.f / (e0 + e1 + e2);
    ssO[r * 3 + 0] = e0 * inv;
    ssO[r * 3 + 1] = e1 * inv;
    ssO[r * 3 + 2] = e2 * inv;
    angO[r * 2 + 0] = q[3] + bang[0];
    angO[r * 2 + 1] = q[4] + bang[1];
    ci_l[t] = q[5] + bc[0];
  }
  __syncthreads();

#pragma unroll
  for (int r = 0; r < ITILE; ++r) {
    const float base = ci_l[r];
    float* orow = contact + (rowbase + i0 + r) * LSEQ;
#pragma unroll
    for (int jc = 0; jc < 2; ++jc) {
      const int j0 = jc * 1024 + t * 4;
      const float4 c4 = *(const float4*)&cj_l[j0];
      f32x4 o;
      o[0] = 1.f / (1.f + __expf(-(base + c4.x)));
      o[1] = 1.f / (1.f + __expf(-(base + c4.y)));
      o[2] = 1.f / (1.f + __expf(-(base + c4.z)));
      o[3] = 1.f / (1.f + __expf(-(base + c4.w)));
      __builtin_nontemporal_store(o, (f32x4*)&orow[j0]);
    }
  }
}

// ---------------------------------------------------------------------------
extern "C" void kernel_launch(void* const* d_in, const int* in_sizes, int n_in,
                              void* d_out, int out_size, void* d_ws, size_t ws_size,
                              hipStream_t stream) {
  const float* X    = (const float*)d_in[0];
  const float* W1   = (const float*)d_in[1];
  const float* b1   = (const float*)d_in[2];
  const float* W2   = (const float*)d_in[3];
  const float* b2   = (const float*)d_in[4];
  const float* Wss  = (const float*)d_in[5];
  const float* bss  = (const float*)d_in[6];
  const float* Wang = (const float*)d_in[7];
  const float* bang = (const float*)d_in[8];
  const float* Wc   = (const float*)d_in[9];
  const float* bc   = (const float*)d_in[10];

  float* out     = (float*)d_out;
  float* ssO     = out;                         // [8192,3]
  float* angO    = out + 24576;                 // [8192,2]
  float* contact = out + 40960;                 // [4,2048,2048]

  ushort* h1  = (ushort*)contact;                        // 8 MB  (swizzled)
  ushort* W2t = (ushort*)(contact + 2 * 1024 * 1024);    // 512 KB (swizzled)
  float* Hpart = (float*)d_ws;                           // [4][7][8192]

  k_prep<<<768, 256, 0, stream>>>(X, W1, b1, W2, h1, W2t);
  k_gemm_heads<<<512, 256, 0, stream>>>(h1, W2t, b2, Wss, Wang, Wc, Hpart);
  k_fc<<<512, 256, 0, stream>>>(Hpart, bss, bang, bc, ssO, angO, contact);
}